// Round 4
// baseline (636.381 us; speedup 1.0000x reference)
//
#include <hip/hip_runtime.h>
#include <stdint.h>

// out[b,s,o] = sum_i x[b,s,i] * (W[o,i] + sum_r A[o,r]*B[r,i]) + bias[o]
// M = 16384, N = 4096, K = 4096. fp32 in/out, bf16 MFMA compute.
// GEMM: 256x256 tile, BK=64, 8 waves, 8-phase deep-pipelined schedule.
// R4: permuted LDS row layout (stage-half == read-phase granule) ->
//     stages issued 6-7 phases ahead of consumption, vmcnt(8) at even phases.

#define MDIM 16384
#define NDIM 4096
#define KDIM 4096
#define RANK 16
#define NT   (KDIM / 64)   // 64 K-tiles

typedef __bf16  bf16x8 __attribute__((ext_vector_type(8)));
typedef float   f32x4  __attribute__((ext_vector_type(4)));
typedef unsigned short u16x8 __attribute__((ext_vector_type(8)));

__device__ __forceinline__ unsigned short f2bf(float f) {
  union { float f; uint32_t u; } v; v.f = f;
  uint32_t r = v.u + 0x7FFFu + ((v.u >> 16) & 1u);
  return (unsigned short)(r >> 16);
}

__device__ __forceinline__ void gl16(const void* g, void* l) {
  __builtin_amdgcn_global_load_lds(
      (__attribute__((address_space(1))) void*)(g),
      (__attribute__((address_space(3))) void*)(l),
      16, 0, 0);
}

// Wp[o][i] = bf16(W[o][i] + sum_r A[o][r]*B[r][i])
__global__ void prep_w(const float* __restrict__ W, const float* __restrict__ A,
                       const float* __restrict__ Bm, unsigned short* __restrict__ Wp) {
  const int i = blockIdx.x * 256 + threadIdx.x;
  const int o = blockIdx.y;
  float acc = W[(size_t)o * NDIM + i];
#pragma unroll
  for (int r = 0; r < RANK; ++r)
    acc += A[o * RANK + r] * Bm[(size_t)r * NDIM + i];
  Wp[(size_t)o * NDIM + i] = f2bf(acc);
}

// x fp32 -> bf16, 8 elems/thread
__global__ void cast_x(const float* __restrict__ x, unsigned short* __restrict__ xb) {
  const size_t i = ((size_t)blockIdx.x * 256 + threadIdx.x) * 8;
  float4 a = *(const float4*)(x + i);
  float4 b = *(const float4*)(x + i + 4);
  u16x8 o;
  o[0] = f2bf(a.x); o[1] = f2bf(a.y); o[2] = f2bf(a.z); o[3] = f2bf(a.w);
  o[4] = f2bf(b.x); o[5] = f2bf(b.y); o[6] = f2bf(b.z); o[7] = f2bf(b.w);
  *(u16x8*)(xb + i) = o;
}

#define BARRIER  __builtin_amdgcn_s_barrier()
#define WAITLGKM asm volatile("s_waitcnt lgkmcnt(0)" ::: "memory")
#define VMCNT8   asm volatile("s_waitcnt vmcnt(8)" ::: "memory")
#define VMCNT6   asm volatile("s_waitcnt vmcnt(6)" ::: "memory")
#define WAITVM0  asm volatile("s_waitcnt vmcnt(0)" ::: "memory")
#define SCHEDB   __builtin_amdgcn_sched_barrier(0)

// ---- staging: one half-tile (128 LDS rows) = 2 x gl16 per thread ----
// A LDS layout: row = mh*128 + wm*64 + (mi*16+lr); stage-half h covers LDS
// rows h*128..h*128+127 <- global rows {h*64+u, 128+h*64+u : u=0..63}.
#define STAGE_A(buf, h, kt) do {                                              \
    const int kc_ = ((kt) < NT ? (kt) : NT - 1);                              \
    const unsigned short* g_ = agb + (size_t)((h) * 64) * KDIM + kc_ * 64;    \
    unsigned short* d_ = &sA[(buf)][0] + (h) * 8192 + t * 8;                  \
    gl16(g_, d_);                                                             \
    gl16(g_ + (size_t)128 * KDIM, d_ + 4096);                                 \
  } while (0)

// B LDS layout: row = nh*128 + wn*32 + (ni*16+lr); stage-half h covers LDS
// rows h*128.. <- global rows {(u>>5)*64 + h*32 + (u&31), +128}.
#define STAGE_B(buf, h, kt) do {                                              \
    const int kc_ = ((kt) < NT ? (kt) : NT - 1);                              \
    const unsigned short* g_ = bgb + (size_t)((h) * 32) * KDIM + kc_ * 64;    \
    unsigned short* d_ = &sB[(buf)][0] + (h) * 8192 + t * 8;                  \
    gl16(g_, d_);                                                             \
    gl16(g_ + (size_t)128 * KDIM, d_ + 4096);                                 \
  } while (0)

// ds_read fragments; element k-offset (kk*32+koff)^xorE, xorE=(row&7)<<3.
#define LDA(buf, mh) do {                                                     \
    _Pragma("unroll") for (int mi = 0; mi < 4; ++mi)                          \
    _Pragma("unroll") for (int kk = 0; kk < 2; ++kk)                          \
      a[mi][kk] = *(const bf16x8*)(saw + (buf)*16384 + ((mh)*128 + mi*16)*64  \
                                   + ((kk*32 + koff) ^ xorE));                \
  } while (0)

#define LDB(buf, nh, bb) do {                                                 \
    _Pragma("unroll") for (int ni = 0; ni < 2; ++ni)                          \
    _Pragma("unroll") for (int kk = 0; kk < 2; ++kk)                          \
      bb[ni][kk] = *(const bf16x8*)(sbw + (buf)*16384 + ((nh)*128 + ni*16)*64 \
                                    + ((kk*32 + koff) ^ xorE));               \
  } while (0)

#define MM(mh, nh, bb) do {                                                   \
    __builtin_amdgcn_s_setprio(1);                                            \
    _Pragma("unroll") for (int mi = 0; mi < 4; ++mi)                          \
    _Pragma("unroll") for (int ni = 0; ni < 2; ++ni)                          \
    _Pragma("unroll") for (int kk = 0; kk < 2; ++kk)                          \
      acc[(mh)*4+mi][(nh)*2+ni] = __builtin_amdgcn_mfma_f32_16x16x32_bf16(    \
          a[mi][kk], bb[ni][kk], acc[(mh)*4+mi][(nh)*2+ni], 0, 0, 0);         \
    __builtin_amdgcn_s_setprio(0);                                            \
  } while (0)

__global__ __launch_bounds__(512, 2) void gemm256(
    const unsigned short* __restrict__ Xb,
    const unsigned short* __restrict__ Wp,
    const float* __restrict__ bias,
    float* __restrict__ out) {
  __shared__ __align__(16) unsigned short sA[2][256 * 64];  // 64 KiB
  __shared__ __align__(16) unsigned short sB[2][256 * 64];  // 64 KiB

  const int t  = threadIdx.x;
  const int l  = t & 63;
  const int w  = t >> 6;   // 0..7
  const int wm = w >> 2;   // 0..1  (m half: 128 rows)
  const int wn = w & 3;    // 0..3  (n quarter: 64 cols)

  // XCD-aware bijective swizzle; n-fastest: each XCD owns an 8-row bm band.
  const int bid = blockIdx.x;
  const int swz = (bid & 7) * (1024 / 8) + (bid >> 3);
  const int bm  = (swz >> 4) * 256;   // 64 m-tiles
  const int bn  = (swz & 15) * 256;   // 16 n-tiles

  // ---- staging bases: thread t -> 16B chunk (t&7) of some row, k inverse-swizzled
  const int sr  = t >> 3;  // LDS-row-within-half 0..63
  const int ske = (((t & 7) * 16) ^ ((sr & 7) << 4)) >> 1;  // bytes -> elements
  const unsigned short* agb = Xb + (size_t)(bm + sr) * KDIM + ske;
  const unsigned short* bgb = Wp + (size_t)(bn + (sr >> 5) * 64 + (sr & 31)) * KDIM + ske;

  // ---- ds_read addressing ----
  const int lr   = l & 15;
  const int koff = (l >> 4) * 8;      // elements
  const int xorE = (lr & 7) << 3;     // elements ((row&7)<<4 bytes)
  const unsigned short* saw = &sA[0][0] + (wm * 64 + lr) * 64;
  const unsigned short* sbw = &sB[0][0] + (wn * 32 + lr) * 64;

  bf16x8 a[4][2], b0[2][2], b1[2][2];
  f32x4 acc[8][4];
#pragma unroll
  for (int i = 0; i < 8; ++i)
#pragma unroll
    for (int j = 0; j < 4; ++j)
      acc[i][j] = f32x4{0.f, 0.f, 0.f, 0.f};

  // ---- prologue: tile0 all 4 halves + tile1 {A.h0,B.h0,B.h1} (14 loads);
  //      vmcnt(6) -> tile0 fully landed, tile1's 3 halves in flight.
  STAGE_A(0, 0, 0); STAGE_B(0, 0, 0); STAGE_A(0, 1, 0); STAGE_B(0, 1, 0);
  STAGE_A(1, 0, 1); STAGE_B(1, 0, 1); STAGE_B(1, 1, 1);
  VMCNT6;
  BARRIER;

  // ---- main loop: 2 K-tiles / iter, 8 phases; stage slots 6-7 phases ahead:
  // ph1: b1.A.h1<-E+1 | ph2: b0.A.h0<-E+2 | ph3: b0.B.h0 | ph4: b0.B.h1
  // ph5: b0.A.h1      | ph6: b1.A.h0<-E+3 | ph7: b1.B.h0 | ph8: b1.B.h1
  for (int it = 0; it < NT / 2; ++it) {
    const int E = it * 2;
    // ph1 (buf0): quadrant 00
    LDA(0, 0); LDB(0, 0, b0);
    STAGE_A(1, 1, E + 1);
    BARRIER; WAITLGKM; SCHEDB;
    MM(0, 0, b0);
    BARRIER;
    // ph2: quadrant 01
    LDB(0, 1, b1);
    STAGE_A(0, 0, E + 2);
    BARRIER; WAITLGKM; SCHEDB;
    MM(0, 1, b1);
    VMCNT8;
    BARRIER;
    // ph3: quadrant 11
    LDA(0, 1);
    STAGE_B(0, 0, E + 2);
    BARRIER; WAITLGKM; SCHEDB;
    MM(1, 1, b1);
    BARRIER;
    // ph4: quadrant 10 (no ds_read)
    STAGE_B(0, 1, E + 2);
    BARRIER;
    MM(1, 0, b0);
    VMCNT8;
    BARRIER;
    // ph5 (buf1): quadrant 00
    LDA(1, 0); LDB(1, 0, b0);
    STAGE_A(0, 1, E + 2);
    BARRIER; WAITLGKM; SCHEDB;
    MM(0, 0, b0);
    BARRIER;
    // ph6: quadrant 01
    LDB(1, 1, b1);
    STAGE_A(1, 0, E + 3);
    BARRIER; WAITLGKM; SCHEDB;
    MM(0, 1, b1);
    VMCNT8;
    BARRIER;
    // ph7: quadrant 11
    LDA(1, 1);
    STAGE_B(1, 0, E + 3);
    BARRIER; WAITLGKM; SCHEDB;
    MM(1, 1, b1);
    BARRIER;
    // ph8: quadrant 10
    STAGE_B(1, 1, E + 3);
    BARRIER;
    MM(1, 0, b0);
    VMCNT8;
    BARRIER;
  }

  WAITVM0;  // drain stray prefetches before LDS dealloc

  // ---- epilogue: C/D layout col=lane&15, row=(lane>>4)*4+reg ----
#pragma unroll
  for (int mf = 0; mf < 8; ++mf) {
#pragma unroll
    for (int nf = 0; nf < 4; ++nf) {
      const int row = bm + wm * 128 + mf * 16 + (l >> 4) * 4;
      const int col = bn + wn * 64 + nf * 16 + lr;
      const float bv = bias[col];
#pragma unroll
      for (int r = 0; r < 4; ++r)
        out[(size_t)(row + r) * NDIM + col] = acc[mf][nf][r] + bv;
    }
  }
}

extern "C" void kernel_launch(void* const* d_in, const int* in_sizes, int n_in,
                              void* d_out, int out_size, void* d_ws, size_t ws_size,
                              hipStream_t stream) {
  const float* x    = (const float*)d_in[0];
  const float* W    = (const float*)d_in[1];
  const float* bias = (const float*)d_in[2];
  const float* A    = (const float*)d_in[3];
  const float* B    = (const float*)d_in[4];
  float* out        = (float*)d_out;

  unsigned short* Wp = (unsigned short*)d_ws;                       // 32 MiB
  unsigned short* Xb = (unsigned short*)d_ws + (size_t)NDIM * KDIM; // 128 MiB

  prep_w<<<dim3(NDIM / 256, NDIM), 256, 0, stream>>>(W, A, B, Wp);
  cast_x<<<dim3((size_t)MDIM * KDIM / (256 * 8)), 256, 0, stream>>>(x, Xb);
  gemm256<<<dim3((MDIM / 256) * (NDIM / 256)), 512, 0, stream>>>(Xb, Wp, bias, out);
}

// Round 5
// 634.090 us; speedup vs baseline: 1.0036x; 1.0036x over previous
//
#include <hip/hip_runtime.h>
#include <stdint.h>

// out[b,s,o] = sum_i x[b,s,i] * (W[o,i] + sum_r A[o,r]*B[r,i]) + bias[o]
// M = 16384, N = 4096, K = 4096. fp32 in/out, bf16 MFMA compute.
// GEMM: 256x256 tile, BK=64, 8 waves, 8-phase deep-pipelined schedule.
// R5: drop explicit lgkmcnt(0)+sched_barrier full drain -> compiler emits
//     counted lgkmcnt per MFMA operand, overlapping LDS drain with MFMA.

#define MDIM 16384
#define NDIM 4096
#define KDIM 4096
#define RANK 16
#define NT   (KDIM / 64)   // 64 K-tiles

typedef __bf16  bf16x8 __attribute__((ext_vector_type(8)));
typedef float   f32x4  __attribute__((ext_vector_type(4)));
typedef unsigned short u16x8 __attribute__((ext_vector_type(8)));

__device__ __forceinline__ unsigned short f2bf(float f) {
  union { float f; uint32_t u; } v; v.f = f;
  uint32_t r = v.u + 0x7FFFu + ((v.u >> 16) & 1u);
  return (unsigned short)(r >> 16);
}

__device__ __forceinline__ void gl16(const void* g, void* l) {
  __builtin_amdgcn_global_load_lds(
      (__attribute__((address_space(1))) void*)(g),
      (__attribute__((address_space(3))) void*)(l),
      16, 0, 0);
}

// Wp[o][i] = bf16(W[o][i] + sum_r A[o][r]*B[r][i])
__global__ void prep_w(const float* __restrict__ W, const float* __restrict__ A,
                       const float* __restrict__ Bm, unsigned short* __restrict__ Wp) {
  const int i = blockIdx.x * 256 + threadIdx.x;
  const int o = blockIdx.y;
  float acc = W[(size_t)o * NDIM + i];
#pragma unroll
  for (int r = 0; r < RANK; ++r)
    acc += A[o * RANK + r] * Bm[(size_t)r * NDIM + i];
  Wp[(size_t)o * NDIM + i] = f2bf(acc);
}

// x fp32 -> bf16, 8 elems/thread
__global__ void cast_x(const float* __restrict__ x, unsigned short* __restrict__ xb) {
  const size_t i = ((size_t)blockIdx.x * 256 + threadIdx.x) * 8;
  float4 a = *(const float4*)(x + i);
  float4 b = *(const float4*)(x + i + 4);
  u16x8 o;
  o[0] = f2bf(a.x); o[1] = f2bf(a.y); o[2] = f2bf(a.z); o[3] = f2bf(a.w);
  o[4] = f2bf(b.x); o[5] = f2bf(b.y); o[6] = f2bf(b.z); o[7] = f2bf(b.w);
  *(u16x8*)(xb + i) = o;
}

#define BARRIER  __builtin_amdgcn_s_barrier()
#define VMCNT8   asm volatile("s_waitcnt vmcnt(8)" ::: "memory")
#define VMCNT6   asm volatile("s_waitcnt vmcnt(6)" ::: "memory")
#define WAITVM0  asm volatile("s_waitcnt vmcnt(0)" ::: "memory")

// ---- staging: one half-tile (128 LDS rows) = 2 x gl16 per thread ----
// A LDS layout: row = mh*128 + wm*64 + (mi*16+lr); stage-half h covers LDS
// rows h*128..h*128+127 <- global rows {h*64+u, 128+h*64+u : u=0..63}.
#define STAGE_A(buf, h, kt) do {                                              \
    const int kc_ = ((kt) < NT ? (kt) : NT - 1);                              \
    const unsigned short* g_ = agb + (size_t)((h) * 64) * KDIM + kc_ * 64;    \
    unsigned short* d_ = &sA[(buf)][0] + (h) * 8192 + t * 8;                  \
    gl16(g_, d_);                                                             \
    gl16(g_ + (size_t)128 * KDIM, d_ + 4096);                                 \
  } while (0)

// B LDS layout: row = nh*128 + wn*32 + (ni*16+lr); stage-half h covers LDS
// rows h*128.. <- global rows {(u>>5)*64 + h*32 + (u&31), +128}.
#define STAGE_B(buf, h, kt) do {                                              \
    const int kc_ = ((kt) < NT ? (kt) : NT - 1);                              \
    const unsigned short* g_ = bgb + (size_t)((h) * 32) * KDIM + kc_ * 64;    \
    unsigned short* d_ = &sB[(buf)][0] + (h) * 8192 + t * 8;                  \
    gl16(g_, d_);                                                             \
    gl16(g_ + (size_t)128 * KDIM, d_ + 4096);                                 \
  } while (0)

// ds_read fragments; element k-offset (kk*32+koff)^xorE, xorE=(row&7)<<3.
// Compiler-visible loads: counted lgkmcnt is inserted per consuming MFMA.
#define LDA(buf, mh) do {                                                     \
    _Pragma("unroll") for (int mi = 0; mi < 4; ++mi)                          \
    _Pragma("unroll") for (int kk = 0; kk < 2; ++kk)                          \
      a[mi][kk] = *(const bf16x8*)(saw + (buf)*16384 + ((mh)*128 + mi*16)*64  \
                                   + ((kk*32 + koff) ^ xorE));                \
  } while (0)

#define LDB(buf, nh, bb) do {                                                 \
    _Pragma("unroll") for (int ni = 0; ni < 2; ++ni)                          \
    _Pragma("unroll") for (int kk = 0; kk < 2; ++kk)                          \
      bb[ni][kk] = *(const bf16x8*)(sbw + (buf)*16384 + ((nh)*128 + ni*16)*64 \
                                    + ((kk*32 + koff) ^ xorE));               \
  } while (0)

#define MM(mh, nh, bb) do {                                                   \
    __builtin_amdgcn_s_setprio(1);                                            \
    _Pragma("unroll") for (int mi = 0; mi < 4; ++mi)                          \
    _Pragma("unroll") for (int ni = 0; ni < 2; ++ni)                          \
    _Pragma("unroll") for (int kk = 0; kk < 2; ++kk)                          \
      acc[(mh)*4+mi][(nh)*2+ni] = __builtin_amdgcn_mfma_f32_16x16x32_bf16(    \
          a[mi][kk], bb[ni][kk], acc[(mh)*4+mi][(nh)*2+ni], 0, 0, 0);         \
    __builtin_amdgcn_s_setprio(0);                                            \
  } while (0)

__global__ __launch_bounds__(512, 2) void gemm256(
    const unsigned short* __restrict__ Xb,
    const unsigned short* __restrict__ Wp,
    const float* __restrict__ bias,
    float* __restrict__ out) {
  __shared__ __align__(16) unsigned short sA[2][256 * 64];  // 64 KiB
  __shared__ __align__(16) unsigned short sB[2][256 * 64];  // 64 KiB

  const int t  = threadIdx.x;
  const int l  = t & 63;
  const int w  = t >> 6;   // 0..7
  const int wm = w >> 2;   // 0..1  (m half: 128 rows)
  const int wn = w & 3;    // 0..3  (n quarter: 64 cols)

  // XCD-aware bijective swizzle; n-fastest: each XCD owns an 8-row bm band.
  const int bid = blockIdx.x;
  const int swz = (bid & 7) * (1024 / 8) + (bid >> 3);
  const int bm  = (swz >> 4) * 256;   // 64 m-tiles
  const int bn  = (swz & 15) * 256;   // 16 n-tiles

  // ---- staging bases: thread t -> 16B chunk (t&7) of some row, k inverse-swizzled
  const int sr  = t >> 3;  // LDS-row-within-half 0..63
  const int ske = (((t & 7) * 16) ^ ((sr & 7) << 4)) >> 1;  // bytes -> elements
  const unsigned short* agb = Xb + (size_t)(bm + sr) * KDIM + ske;
  const unsigned short* bgb = Wp + (size_t)(bn + (sr >> 5) * 64 + (sr & 31)) * KDIM + ske;

  // ---- ds_read addressing ----
  const int lr   = l & 15;
  const int koff = (l >> 4) * 8;      // elements
  const int xorE = (lr & 7) << 3;     // elements ((row&7)<<4 bytes)
  const unsigned short* saw = &sA[0][0] + (wm * 64 + lr) * 64;
  const unsigned short* sbw = &sB[0][0] + (wn * 32 + lr) * 64;

  bf16x8 a[4][2], b0[2][2], b1[2][2];
  f32x4 acc[8][4];
#pragma unroll
  for (int i = 0; i < 8; ++i)
#pragma unroll
    for (int j = 0; j < 4; ++j)
      acc[i][j] = f32x4{0.f, 0.f, 0.f, 0.f};

  // ---- prologue: tile0 all 4 halves + tile1 {A.h0,B.h0,B.h1} (14 loads);
  //      vmcnt(6) -> tile0 fully landed, tile1's 3 halves in flight.
  STAGE_A(0, 0, 0); STAGE_B(0, 0, 0); STAGE_A(0, 1, 0); STAGE_B(0, 1, 0);
  STAGE_A(1, 0, 1); STAGE_B(1, 0, 1); STAGE_B(1, 1, 1);
  VMCNT6;
  BARRIER;

  // ---- main loop: 2 K-tiles / iter, 8 phases; stage slots 6-7 phases ahead:
  // ph1: b1.A.h1<-E+1 | ph2: b0.A.h0<-E+2 | ph3: b0.B.h0 | ph4: b0.B.h1
  // ph5: b0.A.h1      | ph6: b1.A.h0<-E+3 | ph7: b1.B.h0 | ph8: b1.B.h1
  for (int it = 0; it < NT / 2; ++it) {
    const int E = it * 2;
    // ph1 (buf0): quadrant 00
    LDA(0, 0); LDB(0, 0, b0);
    STAGE_A(1, 1, E + 1);
    BARRIER;
    MM(0, 0, b0);
    BARRIER;
    // ph2: quadrant 01
    LDB(0, 1, b1);
    STAGE_A(0, 0, E + 2);
    BARRIER;
    MM(0, 1, b1);
    VMCNT8;
    BARRIER;
    // ph3: quadrant 11
    LDA(0, 1);
    STAGE_B(0, 0, E + 2);
    BARRIER;
    MM(1, 1, b1);
    BARRIER;
    // ph4: quadrant 10 (no ds_read)
    STAGE_B(0, 1, E + 2);
    BARRIER;
    MM(1, 0, b0);
    VMCNT8;
    BARRIER;
    // ph5 (buf1): quadrant 00
    LDA(1, 0); LDB(1, 0, b0);
    STAGE_A(0, 1, E + 2);
    BARRIER;
    MM(0, 0, b0);
    BARRIER;
    // ph6: quadrant 01
    LDB(1, 1, b1);
    STAGE_A(1, 0, E + 3);
    BARRIER;
    MM(0, 1, b1);
    VMCNT8;
    BARRIER;
    // ph7: quadrant 11
    LDA(1, 1);
    STAGE_B(1, 0, E + 3);
    BARRIER;
    MM(1, 1, b1);
    BARRIER;
    // ph8: quadrant 10
    STAGE_B(1, 1, E + 3);
    BARRIER;
    MM(1, 0, b0);
    VMCNT8;
    BARRIER;
  }

  WAITVM0;  // drain stray prefetches before LDS dealloc

  // ---- epilogue: C/D layout col=lane&15, row=(lane>>4)*4+reg ----
#pragma unroll
  for (int mf = 0; mf < 8; ++mf) {
#pragma unroll
    for (int nf = 0; nf < 4; ++nf) {
      const int row = bm + wm * 128 + mf * 16 + (l >> 4) * 4;
      const int col = bn + wn * 64 + nf * 16 + lr;
      const float bv = bias[col];
#pragma unroll
      for (int r = 0; r < 4; ++r)
        out[(size_t)(row + r) * NDIM + col] = acc[mf][nf][r] + bv;
    }
  }
}

extern "C" void kernel_launch(void* const* d_in, const int* in_sizes, int n_in,
                              void* d_out, int out_size, void* d_ws, size_t ws_size,
                              hipStream_t stream) {
  const float* x    = (const float*)d_in[0];
  const float* W    = (const float*)d_in[1];
  const float* bias = (const float*)d_in[2];
  const float* A    = (const float*)d_in[3];
  const float* B    = (const float*)d_in[4];
  float* out        = (float*)d_out;

  unsigned short* Wp = (unsigned short*)d_ws;                       // 32 MiB
  unsigned short* Xb = (unsigned short*)d_ws + (size_t)NDIM * KDIM; // 128 MiB

  prep_w<<<dim3(NDIM / 256, NDIM), 256, 0, stream>>>(W, A, B, Wp);
  cast_x<<<dim3((size_t)MDIM * KDIM / (256 * 8)), 256, 0, stream>>>(x, Xb);
  gemm256<<<dim3((MDIM / 256) * (NDIM / 256)), 512, 0, stream>>>(Xb, Wp, bias, out);
}